// Round 4
// baseline (475.191 us; speedup 1.0000x reference)
//
#include <hip/hip_runtime.h>
#include <cstdint>

#define NPROP  48
#define MGRID  216
#define NPT    (NPROP*MGRID)      // 10368 points per batch
#define KPT    2048
#define CFEAT  128
#define R0SQ   0.64f              // 0.8^2 (f32-rounded same as reference)
#define R1SQ   2.56f              // 1.6^2
#define NS0    16
#define NS1    32
#define KRED   (CFEAT*MGRID)      // 27648
#define NPOINTS (2*NPT)           // 20736

typedef float f4 __attribute__((ext_vector_type(4)));

// workspace layout (floats)
#define HID_SZ   (96*256)                   // 24576
#define Q0_OFF   24576
#define Q1_OFF   (Q0_OFF + 2*KPT*64)        // +262144
#define POOL_OFF (Q1_OFF + 2*KPT*64)        // +262144 ; poolT = [20736 pts][128 ch]
#define W0T_OFF  (POOL_OFF + NPOINTS*CFEAT) // +2654208 ; w0t = [256][27648] g-major
// total = 10,280,960 floats = 41.1 MB

// ---------------------------------------------------------------------------
// K1: w0t[o][g*128+c] = rw0[o][c*216+g]  (one-time weight transpose, 28 MB)
// ---------------------------------------------------------------------------
template <int W>
__device__ __forceinline__ void wtr_tile(const float* __restrict__ src,
                                         float* __restrict__ dst,
                                         float* __restrict__ t, int g0)
{
    const int stride = W + 1;
    for (int idx = threadIdx.x; idx < 128*W; idx += 256) {
        int c = idx / W, gg = idx - c*W;
        t[c*stride + gg] = src[c*216 + g0 + gg];     // coalesced along g
    }
    __syncthreads();
    for (int idx = threadIdx.x; idx < 128*W; idx += 256) {
        int gg = idx >> 7, c = idx & 127;
        dst[(size_t)(g0+gg)*128 + c] = t[c*stride + gg];  // coalesced along c
    }
    __syncthreads();
}

__global__ __launch_bounds__(256) void k_wtr(
    const float* __restrict__ rw0, float* __restrict__ ws)
{
    __shared__ float t[128*65];
    int o = blockIdx.x;
    const float* src = rw0 + (size_t)o*KRED;
    float* dst = ws + W0T_OFF + (size_t)o*KRED;
    wtr_tile<64>(src, dst, t, 0);
    wtr_tile<64>(src, dst, t, 64);
    wtr_tile<64>(src, dst, t, 128);
    wtr_tile<24>(src, dst, t, 192);
}

// ---------------------------------------------------------------------------
// K2: Q[s][b][k][o] = b0_s[o] + sum_i W_s[o][i]*kxyz[b][k][i]
//                            + sum_c W_s[o][3+c]*feats[b][c][k]
// ---------------------------------------------------------------------------
__global__ __launch_bounds__(256) void k_qproj(
    const float* __restrict__ kxyz, const float* __restrict__ feats,
    const float* __restrict__ w0, const float* __restrict__ b0,
    const float* __restrict__ w1, const float* __restrict__ b1,
    float* __restrict__ ws)
{
    __shared__ float wl[64*131];
    int bid  = blockIdx.x;
    int kgrp = bid & 511;
    int s    = (bid >> 9) & 1;
    int b    = bid >> 10;
    const float* W    = s ? w1 : w0;
    const float* bias = s ? b1 : b0;
    for (int i = threadIdx.x; i < 64*131; i += 256) wl[i] = W[i];
    __syncthreads();
    int k = kgrp*4 + (threadIdx.x >> 6);
    int o = threadIdx.x & 63;
    float acc = bias[o];
    const float* kp = kxyz + ((size_t)b*KPT + k)*3;
    acc = fmaf(wl[o*131+0], kp[0], acc);
    acc = fmaf(wl[o*131+1], kp[1], acc);
    acc = fmaf(wl[o*131+2], kp[2], acc);
    const float* f = feats + (size_t)b*CFEAT*KPT + k;
#pragma unroll 8
    for (int c = 0; c < CFEAT; ++c)
        acc = fmaf(wl[o*131+3+c], f[(size_t)c*KPT], acc);
    ws[Q0_OFF + (size_t)s*(2*KPT*64) + ((size_t)b*KPT + k)*64 + o] = acc;
}

// ---------------------------------------------------------------------------
// K3 main: one WAVE per (point, scale): ball query + MLP(Q[k]-u) + maxpool
// ---------------------------------------------------------------------------
__global__ __launch_bounds__(256, 4) void k_main(
    const float* __restrict__ proposals, const float* __restrict__ kxyz,
    const float* __restrict__ grid_noise,
    const float* __restrict__ w00, const float* __restrict__ w01,
    const float* __restrict__ b01,
    const float* __restrict__ w10, const float* __restrict__ w11,
    const float* __restrict__ b11,
    float* __restrict__ ws)
{
    __shared__ int idxs[4][32];
    __shared__ __align__(16) float hb[4][2][64];
    const int wid  = threadIdx.x >> 6;
    const int lane = threadIdx.x & 63;

    // scale-grouped task map: blocks [0,5184) = scale 0, [5184,10368) = scale 1
    const int s = (blockIdx.x >= 5184) ? 1 : 0;
    const int p = (blockIdx.x - s*5184)*4 + wid;   // < 20736
    int b   = p / NPT;
    int rem = p - b*NPT;
    int i   = rem / MGRID;
    int g   = rem - i*MGRID;

    const float* Wl1  = s ? w10 : w00;   // layer-1 (xyz columns)
    const float* Wl2  = s ? w11 : w01;   // layer-2 64x64
    const float* bs   = s ? b11 : b01;
    const float  rsq  = s ? R1SQ : R0SQ;
    const int    ns   = s ? NS1  : NS0;

    float ax = Wl1[lane*131+0], ay = Wl1[lane*131+1], az = Wl1[lane*131+2];

    const float* pr = proposals  + ((size_t)b*NPROP + i)*7;
    const float* gn = grid_noise + (((size_t)b*NPROP + i)*MGRID + g)*3;
    float gx = gn[0]*pr[3], gy = gn[1]*pr[4], gz = gn[2]*pr[5];
    float th = pr[6];
    float ss = sinf(th), cc = cosf(th);
    float nx = cc*gx - ss*gy + pr[0];
    float ny = ss*gx + cc*gy + pr[1];
    float nz = gz + pr[2];
    float pn2 = nx*nx + ny*ny + nz*nz;
    float u = ax*nx + ay*ny + az*nz;

    // ---- ball query: wave-parallel ordered-first-n selection ----
    int* idx = idxs[wid];
    int cnt = 0;
    const float* kb = kxyz + (size_t)b*KPT*3;
    unsigned long long ltm = (1ull << lane) - 1ull;
    for (int ck = 0; ck < KPT/64; ++ck) {
        int kk = ck*64 + lane;
        float kx = kb[kk*3+0], ky = kb[kk*3+1], kz = kb[kk*3+2];
        float kn2 = kx*kx + ky*ky + kz*kz;
        float dt  = nx*kx + ny*ky + nz*kz;
        float d2  = fmaf(-2.f, dt, pn2 + kn2);   // |p|^2+|k|^2-2p.k (ref form)
        unsigned long long m = __ballot(d2 < rsq);
        if (m) {
            int pre = __popcll(m & ltm);
            if (((m >> lane) & 1ull) && cnt + pre < ns) idx[cnt + pre] = kk;
            cnt += __popcll(m);
            if (cnt >= ns) break;                // wave-uniform
        }
    }
    if (lane == 0 && cnt == 0) idx[0] = 0;       // empty-ball fallback
    asm volatile("s_waitcnt lgkmcnt(0)" ::: "memory");
    __builtin_amdgcn_wave_barrier();
    int navail = cnt ? min(cnt, ns) : 1;

    // ---- layer-2 weight row: 16 f4s, pinned in VGPRs via asm (anti-spill)
    const f4* wr = (const f4*)(Wl2 + (size_t)lane*64);
    f4 wv0 = wr[0],  wv1 = wr[1],  wv2 = wr[2],  wv3 = wr[3];
    f4 wv4 = wr[4],  wv5 = wr[5],  wv6 = wr[6],  wv7 = wr[7];
    f4 wv8 = wr[8],  wv9 = wr[9],  wv10 = wr[10], wv11 = wr[11];
    f4 wv12 = wr[12], wv13 = wr[13], wv14 = wr[14], wv15 = wr[15];
    float bias = bs[lane];

#define PIN_W asm volatile("" : "+v"(wv0), "+v"(wv1), "+v"(wv2), "+v"(wv3),   \
        "+v"(wv4), "+v"(wv5), "+v"(wv6), "+v"(wv7), "+v"(wv8), "+v"(wv9),     \
        "+v"(wv10), "+v"(wv11), "+v"(wv12), "+v"(wv13), "+v"(wv14), "+v"(wv15))

    // ---- MLP + maxpool (clamped duplicate samples are max-neutral)
    const float* Qb = ws + Q0_OFF + (size_t)s*(2*KPT*64) + (size_t)b*(KPT*64);
    float* hb0 = hb[wid][0];
    float* hb1 = hb[wid][1];
    float mx = 0.f;
    int nm1 = navail - 1;

    float qcur = Qb[((size_t)idx[0] << 6) + lane];
    int t1 = (1 < nm1) ? 1 : nm1;
    float qn1 = Qb[((size_t)idx[t1] << 6) + lane];

#define DOT(J,W) { f4 h4 = hv[J];                                             \
        a0 = fmaf(W.x, h4.x, a0); a1 = fmaf(W.y, h4.y, a1);                   \
        a2 = fmaf(W.z, h4.z, a2); a3 = fmaf(W.w, h4.w, a3); }

#pragma unroll 4
    for (int t = 0; t < ns; ++t) {               // ns in {16,32}, %4 == 0
        PIN_W;
        int tn2 = t + 2; if (tn2 > nm1) tn2 = nm1;
        float qn2 = Qb[((size_t)idx[tn2] << 6) + lane];
        float h1 = fmaxf(qcur - u, 0.f);
        float* hw = (t & 1) ? hb1 : hb0;
        hw[lane] = h1;                           // lane o writes h1[o]
        __builtin_amdgcn_wave_barrier();         // keep write before the reads
        const f4* hv = (const f4*)hw;
        float a0 = bias, a1 = 0.f, a2 = 0.f, a3 = 0.f;
        DOT(0,wv0)  DOT(1,wv1)  DOT(2,wv2)  DOT(3,wv3)
        DOT(4,wv4)  DOT(5,wv5)  DOT(6,wv6)  DOT(7,wv7)
        DOT(8,wv8)  DOT(9,wv9)  DOT(10,wv10) DOT(11,wv11)
        DOT(12,wv12) DOT(13,wv13) DOT(14,wv14) DOT(15,wv15)
        __builtin_amdgcn_wave_barrier();         // keep reads before next write
        float acc = (a0 + a1) + (a2 + a3);
        mx = fmaxf(mx, fmaxf(acc, 0.f));
        qcur = qn1; qn1 = qn2;
    }
#undef DOT
#undef PIN_W

    // coalesced pooled store: poolT[p][s*64+lane], 256 B contiguous per wave
    ws[POOL_OFF + (size_t)p*CFEAT + s*64 + lane] = mx;
}

// ---------------------------------------------------------------------------
// K4: hid[96][256] += A[96][27648] * B[256][27648]^T   (K-split, atomicAdd)
// A = poolT viewed as [96][216*128] (g-major), B = w0t (g-major) -> same dot
// grid = 216 ksplits x 2 o-tiles; block 256; per-thread 6r x 8o accumulators
// ---------------------------------------------------------------------------
__global__ __launch_bounds__(256) void k_red0(
    const float* __restrict__ A, const float* __restrict__ w0,
    float* __restrict__ hid)
{
    __shared__ __align__(16) float Al[96*68];
    __shared__ __align__(16) float Bl[128*68];
    int bid = blockIdx.x;
    int ot  = bid & 1;
    int ks  = bid >> 1;                      // 0..215
    int tid = threadIdx.x;
    int tx  = tid & 15, ty = tid >> 4;       // ty in [0,16): 6 rows each
    float acc[6][8] = {};

    for (int chunk = 0; chunk < 2; ++chunk) {
        int kk0 = ks*128 + chunk*64;
#pragma unroll
        for (int j = 0; j < 6; ++j) {        // stage A 96x64
            int f4i = tid + j*256;
            int rr = f4i >> 4, c4 = f4i & 15;
            float4 v = *(const float4*)(A + (size_t)rr*KRED + kk0 + c4*4);
            *(float4*)(Al + rr*68 + c4*4) = v;
        }
#pragma unroll
        for (int j = 0; j < 8; ++j) {        // stage B 128x64
            int f4i = tid + j*256;
            int rr = f4i >> 4, c4 = f4i & 15;
            float4 v = *(const float4*)(w0 + (size_t)(ot*128+rr)*KRED + kk0 + c4*4);
            *(float4*)(Bl + rr*68 + c4*4) = v;
        }
        __syncthreads();
#pragma unroll
        for (int k4 = 0; k4 < 16; ++k4) {
            float4 av[6], bv[8];
#pragma unroll
            for (int q = 0; q < 6; ++q) av[q] = *(const float4*)(Al + (ty*6+q)*68 + k4*4);
#pragma unroll
            for (int u = 0; u < 8; ++u) bv[u] = *(const float4*)(Bl + (u*16+tx)*68 + k4*4);
#pragma unroll
            for (int q = 0; q < 6; ++q)
#pragma unroll
                for (int u = 0; u < 8; ++u) {
                    acc[q][u] = fmaf(av[q].x, bv[u].x, acc[q][u]);
                    acc[q][u] = fmaf(av[q].y, bv[u].y, acc[q][u]);
                    acc[q][u] = fmaf(av[q].z, bv[u].z, acc[q][u]);
                    acc[q][u] = fmaf(av[q].w, bv[u].w, acc[q][u]);
                }
        }
        __syncthreads();
    }
#pragma unroll
    for (int q = 0; q < 6; ++q)
#pragma unroll
        for (int u = 0; u < 8; ++u)
            atomicAdd(hid + (size_t)(ty*6+q)*256 + ot*128 + u*16 + tx, acc[q][u]);
}

// ---------------------------------------------------------------------------
// K5: out = relu(relu(hid + b0) @ W1^T + b1)
// ---------------------------------------------------------------------------
__global__ __launch_bounds__(256) void k_fin(
    const float* __restrict__ hid, const float* __restrict__ rb0,
    const float* __restrict__ w1, const float* __restrict__ rb1,
    float* __restrict__ out)
{
    __shared__ __align__(16) float hbuf[256];
    int r = blockIdx.x, o = threadIdx.x;
    float h = fmaxf(hid[(size_t)r*256 + o] + rb0[o], 0.f);
    hbuf[o] = h;
    __syncthreads();
    float a0 = rb1[o], a1 = 0.f, a2 = 0.f, a3 = 0.f;
    const float4* wrow = (const float4*)(w1 + (size_t)o*256);
    const float4* hv   = (const float4*)hbuf;
#pragma unroll 8
    for (int j = 0; j < 64; ++j) {
        float4 w = wrow[j], x = hv[j];
        a0 = fmaf(w.x, x.x, a0);
        a1 = fmaf(w.y, x.y, a1);
        a2 = fmaf(w.z, x.z, a2);
        a3 = fmaf(w.w, x.w, a3);
    }
    out[(size_t)r*256 + o] = fmaxf((a0 + a1) + (a2 + a3), 0.f);
}

// ---------------------------------------------------------------------------
extern "C" void kernel_launch(void* const* d_in, const int* in_sizes, int n_in,
                              void* d_out, int out_size, void* d_ws, size_t ws_size,
                              hipStream_t stream)
{
    (void)in_sizes; (void)n_in; (void)out_size; (void)ws_size;
    const float* proposals = (const float*)d_in[0];
    const float* kxyz      = (const float*)d_in[1];
    const float* feats     = (const float*)d_in[2];
    const float* gnoise    = (const float*)d_in[3];
    const float* w0_0 = (const float*)d_in[4];
    const float* b0_0 = (const float*)d_in[5];
    const float* w0_1 = (const float*)d_in[6];
    const float* b0_1 = (const float*)d_in[7];
    const float* w1_0 = (const float*)d_in[8];
    const float* b1_0 = (const float*)d_in[9];
    const float* w1_1 = (const float*)d_in[10];
    const float* b1_1 = (const float*)d_in[11];
    const float* rw0  = (const float*)d_in[12];
    const float* rb0  = (const float*)d_in[13];
    const float* rw1  = (const float*)d_in[14];
    const float* rb1  = (const float*)d_in[15];
    float* ws  = (float*)d_ws;
    float* out = (float*)d_out;

    hipMemsetAsync(ws, 0, HID_SZ*sizeof(float), stream);                 // hid = 0
    k_wtr  <<< 256, 256, 0, stream>>>(rw0, ws);
    k_qproj<<<2048, 256, 0, stream>>>(kxyz, feats, w0_0, b0_0, w1_0, b1_0, ws);
    k_main <<<10368, 256, 0, stream>>>(proposals, kxyz, gnoise,
                                       w0_0, w0_1, b0_1, w1_0, w1_1, b1_1, ws);
    k_red0 <<< 432, 256, 0, stream>>>(ws + POOL_OFF, ws + W0T_OFF, ws);
    k_fin  <<<  96, 256, 0, stream>>>(ws, rb0, rw1, rb1, out);
}

// Round 5
// 281.928 us; speedup vs baseline: 1.6855x; 1.6855x over previous
//
#include <hip/hip_runtime.h>
#include <cstdint>

#define NPROP  48
#define MGRID  216
#define NPT    (NPROP*MGRID)      // 10368 points per batch
#define KPT    2048
#define CFEAT  128
#define R0SQ   0.64f              // 0.8^2 (f32-rounded same as reference)
#define R1SQ   2.56f              // 1.6^2
#define NS0    16
#define NS1    32
#define KRED   (CFEAT*MGRID)      // 27648
#define NPOINTS (2*NPT)           // 20736

typedef float f32x4  __attribute__((ext_vector_type(4)));
typedef short bf16x8 __attribute__((ext_vector_type(8)));

// workspace layout (floats)
#define AFRAG_OFF 0                          // 2048 bf16x8 = 8192 floats
#define HID_SZ    (96*256)
#define HID_OFF   8192
#define Q0_OFF    (HID_OFF + HID_SZ)         // 32768 ; Q = [2 scale][2 b][2048 k][64 o]
#define POOL_OFF  (Q0_OFF + 4*KPT*64)        // 557056 ; poolT = [20736 pts][128 ch]
#define W0T_OFF   (POOL_OFF + NPOINTS*CFEAT) // 3211264 ; w0t = [256][27648] g-major
// end = 10,289,152 floats = 41.2 MB

__device__ __forceinline__ unsigned short bf_rne(float x) {
    unsigned u = __float_as_uint(x);
    return (unsigned short)((u + 0x7fffu + ((u >> 16) & 1u)) >> 16);
}
__device__ __forceinline__ float bf_f32(unsigned short h) {
    return __uint_as_float(((unsigned)h) << 16);
}

// ---------------------------------------------------------------------------
// K0: precompute layer-2 weight MFMA A-fragments (hi/lo bf16 split).
// A-frag (16x16x32): lane l holds A[m = l&15][k = (l>>4)*8 + j], j=0..7.
// frag id fi = ((s*4 + ot)*2 + kc): tile row ot*16, k-chunk kc*32.
// ---------------------------------------------------------------------------
__global__ __launch_bounds__(64) void k_wfrag(
    const float* __restrict__ w01, const float* __restrict__ w11,
    float* __restrict__ ws)
{
    int bid = blockIdx.x;
    int kc = bid & 1, ot = (bid >> 1) & 3, s = bid >> 3;
    const float* W = s ? w11 : w01;
    int l   = threadIdx.x;
    int row = ot*16 + (l & 15);
    int k0  = kc*32 + (l >> 4)*8;
    union { unsigned short u16[8]; bf16x8 v; } hh, hl;
#pragma unroll
    for (int j = 0; j < 8; ++j) {
        float x  = W[row*64 + k0 + j];
        unsigned short hi = bf_rne(x);
        float xl = x - bf_f32(hi);
        hh.u16[j] = hi;
        hl.u16[j] = bf_rne(xl);
    }
    bf16x8* Ahi = (bf16x8*)(ws + AFRAG_OFF);
    bf16x8* Alo = Ahi + 16*64;
    int fi = (s*4 + ot)*2 + kc;
    Ahi[fi*64 + l] = hh.v;
    Alo[fi*64 + l] = hl.v;
}

// ---------------------------------------------------------------------------
// K1: w0t[o][g*128+c] = rw0[o][c*216+g]  (one-time weight transpose, 28 MB)
// ---------------------------------------------------------------------------
template <int W>
__device__ __forceinline__ void wtr_tile(const float* __restrict__ src,
                                         float* __restrict__ dst,
                                         float* __restrict__ t, int g0)
{
    const int stride = W + 1;
    for (int idx = threadIdx.x; idx < 128*W; idx += 256) {
        int c = idx / W, gg = idx - c*W;
        t[c*stride + gg] = src[c*216 + g0 + gg];
    }
    __syncthreads();
    for (int idx = threadIdx.x; idx < 128*W; idx += 256) {
        int gg = idx >> 7, c = idx & 127;
        dst[(size_t)(g0+gg)*128 + c] = t[c*stride + gg];
    }
    __syncthreads();
}

__global__ __launch_bounds__(256) void k_wtr(
    const float* __restrict__ rw0, float* __restrict__ ws)
{
    __shared__ float t[128*65];
    int o = blockIdx.x;
    const float* src = rw0 + (size_t)o*KRED;
    float* dst = ws + W0T_OFF + (size_t)o*KRED;
    wtr_tile<64>(src, dst, t, 0);
    wtr_tile<64>(src, dst, t, 64);
    wtr_tile<64>(src, dst, t, 128);
    wtr_tile<24>(src, dst, t, 192);
}

// ---------------------------------------------------------------------------
// K2: Q[s][b][k][o] = b0_s[o] + W_s[o][0:3].kxyz + W_s[o][3:].feats
// ---------------------------------------------------------------------------
__global__ __launch_bounds__(256) void k_qproj(
    const float* __restrict__ kxyz, const float* __restrict__ feats,
    const float* __restrict__ w0, const float* __restrict__ b0,
    const float* __restrict__ w1, const float* __restrict__ b1,
    float* __restrict__ ws)
{
    __shared__ float wl[64*131];
    int bid  = blockIdx.x;
    int kgrp = bid & 511;
    int s    = (bid >> 9) & 1;
    int b    = bid >> 10;
    const float* W    = s ? w1 : w0;
    const float* bias = s ? b1 : b0;
    for (int i = threadIdx.x; i < 64*131; i += 256) wl[i] = W[i];
    __syncthreads();
    int k = kgrp*4 + (threadIdx.x >> 6);
    int o = threadIdx.x & 63;
    float acc = bias[o];
    const float* kp = kxyz + ((size_t)b*KPT + k)*3;
    acc = fmaf(wl[o*131+0], kp[0], acc);
    acc = fmaf(wl[o*131+1], kp[1], acc);
    acc = fmaf(wl[o*131+2], kp[2], acc);
    const float* f = feats + (size_t)b*CFEAT*KPT + k;
#pragma unroll 8
    for (int c = 0; c < CFEAT; ++c)
        acc = fmaf(wl[o*131+3+c], f[(size_t)c*KPT], acc);
    ws[Q0_OFF + (size_t)s*(2*KPT*64) + ((size_t)b*KPT + k)*64 + o] = acc;
}

// ---------------------------------------------------------------------------
// K3 main: one WAVE per (point, scale): ball query + MFMA layer-2 + maxpool
// ---------------------------------------------------------------------------
template <int NST>
__device__ __forceinline__ void mfma_tail(
    const float* __restrict__ Qb, const bf16x8* __restrict__ Ahi,
    const bf16x8* __restrict__ Alo, const float* __restrict__ bs,
    const int* __restrict__ idxl, const float* __restrict__ u_lds,
    float* __restrict__ stage, int sbase, int lane)
{
    const int g = lane >> 4;
    // ---- build B fragments: lane holds h[k=(g*8+j)+kc*32][sample=st*16+(lane&15)]
    bf16x8 Bhi[NST][2], Blo[NST][2];
#pragma unroll
    for (int st = 0; st < NST; ++st) {
        int sp = idxl[st*16 + (lane & 15)];
        const float* qr = Qb + ((size_t)sp << 6) + g*8;
#pragma unroll
        for (int kc = 0; kc < 2; ++kc) {
            f32x4 q0 = *(const f32x4*)(qr + kc*32);
            f32x4 q1 = *(const f32x4*)(qr + kc*32 + 4);
            f32x4 u0 = *(const f32x4*)(u_lds + kc*32 + g*8);
            f32x4 u1 = *(const f32x4*)(u_lds + kc*32 + g*8 + 4);
            union { unsigned short u16[8]; bf16x8 v; } hh, hl;
#pragma unroll
            for (int j = 0; j < 4; ++j) {
                float x = fmaxf(q0[j] - u0[j], 0.f);
                unsigned short hi = bf_rne(x);
                hh.u16[j] = hi;
                hl.u16[j] = bf_rne(x - bf_f32(hi));
                float y = fmaxf(q1[j] - u1[j], 0.f);
                unsigned short hi2 = bf_rne(y);
                hh.u16[j+4] = hi2;
                hl.u16[j+4] = bf_rne(y - bf_f32(hi2));
            }
            Bhi[st][kc] = hh.v;
            Blo[st][kc] = hl.v;
        }
    }
    // ---- 4 output tiles of 16 channels each
#pragma unroll
    for (int ot = 0; ot < 4; ++ot) {
        int fi = (sbase + ot)*2;
        bf16x8 ah0 = Ahi[(fi+0)*64 + lane];
        bf16x8 ah1 = Ahi[(fi+1)*64 + lane];
        bf16x8 al0 = Alo[(fi+0)*64 + lane];
        bf16x8 al1 = Alo[(fi+1)*64 + lane];
        f32x4 bv = *(const f32x4*)(bs + ot*16 + g*4);
        f32x4 rmax = {0.f, 0.f, 0.f, 0.f};          // relu >= 0
#pragma unroll
        for (int st = 0; st < NST; ++st) {
            f32x4 acc = {0.f, 0.f, 0.f, 0.f};
            acc = __builtin_amdgcn_mfma_f32_16x16x32_bf16(al0, Bhi[st][0], acc, 0,0,0);
            acc = __builtin_amdgcn_mfma_f32_16x16x32_bf16(al1, Bhi[st][1], acc, 0,0,0);
            acc = __builtin_amdgcn_mfma_f32_16x16x32_bf16(ah0, Blo[st][0], acc, 0,0,0);
            acc = __builtin_amdgcn_mfma_f32_16x16x32_bf16(ah1, Blo[st][1], acc, 0,0,0);
            acc = __builtin_amdgcn_mfma_f32_16x16x32_bf16(ah0, Bhi[st][0], acc, 0,0,0);
            acc = __builtin_amdgcn_mfma_f32_16x16x32_bf16(ah1, Bhi[st][1], acc, 0,0,0);
#pragma unroll
            for (int r = 0; r < 4; ++r)
                rmax[r] = fmaxf(rmax[r], fmaxf(acc[r] + bv[r], 0.f));
        }
        // max over C columns (= samples): xor-reduce lanes 0..3 bits
#pragma unroll
        for (int m = 1; m < 16; m <<= 1) {
#pragma unroll
            for (int r = 0; r < 4; ++r)
                rmax[r] = fmaxf(rmax[r], __shfl_xor(rmax[r], m));
        }
        if ((lane & 15) == 0)                        // rows g*4+r of tile ot
            *(f32x4*)(stage + ot*16 + g*4) = rmax;
    }
}

__global__ __launch_bounds__(256, 3) void k_main(
    const float* __restrict__ proposals, const float* __restrict__ kxyz,
    const float* __restrict__ grid_noise,
    const float* __restrict__ w00, const float* __restrict__ b01,
    const float* __restrict__ w10, const float* __restrict__ b11,
    float* __restrict__ ws)
{
    __shared__ int idxs[4][32];
    __shared__ __align__(16) float u_lds[4][64];
    __shared__ __align__(16) float stage[4][64];
    const int wid  = threadIdx.x >> 6;
    const int lane = threadIdx.x & 63;

    // scale-grouped task map: blocks [0,5184) = scale 0, [5184,10368) = scale 1
    const int s = (blockIdx.x >= 5184) ? 1 : 0;
    const int p = (blockIdx.x - s*5184)*4 + wid;   // < 20736
    int b   = p / NPT;
    int rem = p - b*NPT;
    int i   = rem / MGRID;
    int g   = rem - i*MGRID;

    const float* Wl1 = s ? w10 : w00;
    const float* bs  = s ? b11 : b01;
    const float rsq  = s ? R1SQ : R0SQ;
    const int   ns   = s ? NS1  : NS0;

    float ax = Wl1[lane*131+0], ay = Wl1[lane*131+1], az = Wl1[lane*131+2];

    const float* pr = proposals  + ((size_t)b*NPROP + i)*7;
    const float* gn = grid_noise + (((size_t)b*NPROP + i)*MGRID + g)*3;
    float gx = gn[0]*pr[3], gy = gn[1]*pr[4], gz = gn[2]*pr[5];
    float th = pr[6];
    float ss = sinf(th), cc = cosf(th);
    float nx = cc*gx - ss*gy + pr[0];
    float ny = ss*gx + cc*gy + pr[1];
    float nz = gz + pr[2];
    float pn2 = nx*nx + ny*ny + nz*nz;
    float u = ax*nx + ay*ny + az*nz;

    // ---- ball query: wave-parallel ordered-first-n selection ----
    int* idx = idxs[wid];
    int cnt = 0;
    const float* kb = kxyz + (size_t)b*KPT*3;
    unsigned long long ltm = (1ull << lane) - 1ull;
    for (int ck = 0; ck < KPT/64; ++ck) {
        int kk = ck*64 + lane;
        float kx = kb[kk*3+0], ky = kb[kk*3+1], kz = kb[kk*3+2];
        float kn2 = kx*kx + ky*ky + kz*kz;
        float dt  = nx*kx + ny*ky + nz*kz;
        float d2  = fmaf(-2.f, dt, pn2 + kn2);   // |p|^2+|k|^2-2p.k (ref form)
        unsigned long long m = __ballot(d2 < rsq);
        if (m) {
            int pre = __popcll(m & ltm);
            if (((m >> lane) & 1ull) && cnt + pre < ns) idx[cnt + pre] = kk;
            cnt += __popcll(m);
            if (cnt >= ns) break;                // wave-uniform
        }
    }
    if (lane == 0 && cnt == 0) idx[0] = 0;       // empty-ball fallback
    u_lds[wid][lane] = u;
    asm volatile("s_waitcnt lgkmcnt(0)" ::: "memory");
    __builtin_amdgcn_wave_barrier();
    int navail = cnt ? min(cnt, ns) : 1;
    int first  = idx[0];
    if (lane >= navail && lane < ns) idx[lane] = first;  // pad like reference
    asm volatile("s_waitcnt lgkmcnt(0)" ::: "memory");
    __builtin_amdgcn_wave_barrier();

    // ---- MFMA layer-2 + pool
    const float*  Qb  = ws + Q0_OFF + (size_t)s*(2*KPT*64) + (size_t)b*(KPT*64);
    const bf16x8* Ahi = (const bf16x8*)(ws + AFRAG_OFF);
    const bf16x8* Alo = Ahi + 16*64;
    if (s == 0)
        mfma_tail<1>(Qb, Ahi, Alo, bs, idx, u_lds[wid], stage[wid], 0, lane);
    else
        mfma_tail<2>(Qb, Ahi, Alo, bs, idx, u_lds[wid], stage[wid], 4, lane);

    asm volatile("s_waitcnt lgkmcnt(0)" ::: "memory");
    __builtin_amdgcn_wave_barrier();
    float mx = stage[wid][lane];

    // coalesced pooled store: poolT[p][s*64+lane]
    ws[POOL_OFF + (size_t)p*CFEAT + s*64 + lane] = mx;
}

// ---------------------------------------------------------------------------
// K4: hid[96][256] += A[96][27648] * B[256][27648]^T   (K-split, atomicAdd)
// ---------------------------------------------------------------------------
__global__ __launch_bounds__(256) void k_red0(
    const float* __restrict__ A, const float* __restrict__ w0,
    float* __restrict__ hid)
{
    __shared__ __align__(16) float Al[96*68];
    __shared__ __align__(16) float Bl[128*68];
    int bid = blockIdx.x;
    int ot  = bid & 1;
    int ks  = bid >> 1;                      // 0..215
    int tid = threadIdx.x;
    int tx  = tid & 15, ty = tid >> 4;
    float acc[6][8] = {};

    for (int chunk = 0; chunk < 2; ++chunk) {
        int kk0 = ks*128 + chunk*64;
#pragma unroll
        for (int j = 0; j < 6; ++j) {
            int f4i = tid + j*256;
            int rr = f4i >> 4, c4 = f4i & 15;
            float4 v = *(const float4*)(A + (size_t)rr*KRED + kk0 + c4*4);
            *(float4*)(Al + rr*68 + c4*4) = v;
        }
#pragma unroll
        for (int j = 0; j < 8; ++j) {
            int f4i = tid + j*256;
            int rr = f4i >> 4, c4 = f4i & 15;
            float4 v = *(const float4*)(w0 + (size_t)(ot*128+rr)*KRED + kk0 + c4*4);
            *(float4*)(Bl + rr*68 + c4*4) = v;
        }
        __syncthreads();
#pragma unroll
        for (int k4 = 0; k4 < 16; ++k4) {
            float4 av[6], bv[8];
#pragma unroll
            for (int q = 0; q < 6; ++q) av[q] = *(const float4*)(Al + (ty*6+q)*68 + k4*4);
#pragma unroll
            for (int u = 0; u < 8; ++u) bv[u] = *(const float4*)(Bl + (u*16+tx)*68 + k4*4);
#pragma unroll
            for (int q = 0; q < 6; ++q)
#pragma unroll
                for (int u = 0; u < 8; ++u) {
                    acc[q][u] = fmaf(av[q].x, bv[u].x, acc[q][u]);
                    acc[q][u] = fmaf(av[q].y, bv[u].y, acc[q][u]);
                    acc[q][u] = fmaf(av[q].z, bv[u].z, acc[q][u]);
                    acc[q][u] = fmaf(av[q].w, bv[u].w, acc[q][u]);
                }
        }
        __syncthreads();
    }
#pragma unroll
    for (int q = 0; q < 6; ++q)
#pragma unroll
        for (int u = 0; u < 8; ++u)
            atomicAdd(hid + (size_t)(ty*6+q)*256 + ot*128 + u*16 + tx, acc[q][u]);
}

// ---------------------------------------------------------------------------
// K5: out = relu(relu(hid + b0) @ W1^T + b1)
// ---------------------------------------------------------------------------
__global__ __launch_bounds__(256) void k_fin(
    const float* __restrict__ hid, const float* __restrict__ rb0,
    const float* __restrict__ w1, const float* __restrict__ rb1,
    float* __restrict__ out)
{
    __shared__ __align__(16) float hbuf[256];
    int r = blockIdx.x, o = threadIdx.x;
    float h = fmaxf(hid[(size_t)r*256 + o] + rb0[o], 0.f);
    hbuf[o] = h;
    __syncthreads();
    float a0 = rb1[o], a1 = 0.f, a2 = 0.f, a3 = 0.f;
    const float4* wrow = (const float4*)(w1 + (size_t)o*256);
    const float4* hv   = (const float4*)hbuf;
#pragma unroll 8
    for (int j = 0; j < 64; ++j) {
        float4 w = wrow[j], x = hv[j];
        a0 = fmaf(w.x, x.x, a0);
        a1 = fmaf(w.y, x.y, a1);
        a2 = fmaf(w.z, x.z, a2);
        a3 = fmaf(w.w, x.w, a3);
    }
    out[(size_t)r*256 + o] = fmaxf((a0 + a1) + (a2 + a3), 0.f);
}

// ---------------------------------------------------------------------------
extern "C" void kernel_launch(void* const* d_in, const int* in_sizes, int n_in,
                              void* d_out, int out_size, void* d_ws, size_t ws_size,
                              hipStream_t stream)
{
    (void)in_sizes; (void)n_in; (void)out_size; (void)ws_size;
    const float* proposals = (const float*)d_in[0];
    const float* kxyz      = (const float*)d_in[1];
    const float* feats     = (const float*)d_in[2];
    const float* gnoise    = (const float*)d_in[3];
    const float* w0_0 = (const float*)d_in[4];
    const float* b0_0 = (const float*)d_in[5];
    const float* w0_1 = (const float*)d_in[6];
    const float* b0_1 = (const float*)d_in[7];
    const float* w1_0 = (const float*)d_in[8];
    const float* b1_0 = (const float*)d_in[9];
    const float* w1_1 = (const float*)d_in[10];
    const float* b1_1 = (const float*)d_in[11];
    const float* rw0  = (const float*)d_in[12];
    const float* rb0  = (const float*)d_in[13];
    const float* rw1  = (const float*)d_in[14];
    const float* rb1  = (const float*)d_in[15];
    float* ws  = (float*)d_ws;
    float* out = (float*)d_out;

    hipMemsetAsync(ws + HID_OFF, 0, HID_SZ*sizeof(float), stream);       // hid = 0
    k_wfrag<<<  16,  64, 0, stream>>>(w0_1, w1_1, ws);
    k_wtr  <<< 256, 256, 0, stream>>>(rw0, ws);
    k_qproj<<<2048, 256, 0, stream>>>(kxyz, feats, w0_0, b0_0, w1_0, b1_0, ws);
    k_main <<<10368, 256, 0, stream>>>(proposals, kxyz, gnoise,
                                       w0_0, b0_1, w1_0, b1_1, ws);
    k_red0 <<< 432, 256, 0, stream>>>(ws + POOL_OFF, ws + W0T_OFF, ws + HID_OFF);
    k_fin  <<<  96, 256, 0, stream>>>(ws + HID_OFF, rb0, rw1, rb1, out);
}

// Round 6
// 258.983 us; speedup vs baseline: 1.8348x; 1.0886x over previous
//
#include <hip/hip_runtime.h>
#include <cstdint>

#define NPROP  48
#define MGRID  216
#define NPT    (NPROP*MGRID)      // 10368 points per batch
#define KPT    2048
#define CFEAT  128
#define R0SQ   0.64f              // 0.8^2
#define R1SQ   2.56f              // 1.6^2
#define NS0    16
#define NS1    32
#define KRED   (CFEAT*MGRID)      // 27648
#define NPOINTS (2*NPT)           // 20736
#define NKSPLIT 108               // K per split = 256

typedef float f32x4  __attribute__((ext_vector_type(4)));
typedef short bf16x8 __attribute__((ext_vector_type(8)));
typedef unsigned long long ull;

// workspace layout (floats) — total 8,511,488 fl = 34.0 MB (proven budget 41 MB)
#define AFRAG_OFF 0                           // A-frags hi+lo: 8192 floats
#define KX4_OFF   8192                        // kxyz4 [2][2048] f32x4 = 16384
#define Q0_OFF    24576                       // Q [2 s][2 b][2048 k][64 o] = 524288
#define POOL_OFF  548864                      // poolT [20736 p][128 c] = 2654208
#define PT_OFF    3203072                     // pool2 [96 r][27648 (c*216+g)] = 2654208
#define PART_OFF  5857280                     // part [108 ks][96 r][256 o] = 2654208

__device__ __forceinline__ unsigned short bf_rne(float x) {
    unsigned u = __float_as_uint(x);
    return (unsigned short)((u + 0x7fffu + ((u >> 16) & 1u)) >> 16);
}
__device__ __forceinline__ float bf_f32(unsigned short h) {
    return __uint_as_float(((unsigned)h) << 16);
}

// ---------------------------------------------------------------------------
// K0: blocks 0-15: layer-2 weight A-fragments (hi/lo bf16 split).
//     blocks 16-79: pack kxyz4 = (x,y,z,kn2) for the ball query.
// ---------------------------------------------------------------------------
__global__ __launch_bounds__(64) void k_pre(
    const float* __restrict__ kxyz,
    const float* __restrict__ w01, const float* __restrict__ w11,
    float* __restrict__ ws)
{
    int bid = blockIdx.x;
    if (bid < 16) {
        int kc = bid & 1, ot = (bid >> 1) & 3, s = bid >> 3;
        const float* W = s ? w11 : w01;
        int l   = threadIdx.x;
        int row = ot*16 + (l & 15);
        int k0  = kc*32 + (l >> 4)*8;
        union { unsigned short u16[8]; bf16x8 v; } hh, hl;
#pragma unroll
        for (int j = 0; j < 8; ++j) {
            float x  = W[row*64 + k0 + j];
            unsigned short hi = bf_rne(x);
            hh.u16[j] = hi;
            hl.u16[j] = bf_rne(x - bf_f32(hi));
        }
        bf16x8* Ahi = (bf16x8*)(ws + AFRAG_OFF);
        bf16x8* Alo = Ahi + 16*64;
        int fi = (s*4 + ot)*2 + kc;
        Ahi[fi*64 + l] = hh.v;
        Alo[fi*64 + l] = hl.v;
    } else {
        int idx = (bid - 16)*64 + threadIdx.x;      // = b*KPT + k, < 4096
        const float* kp = kxyz + (size_t)idx*3;
        float kx = kp[0], ky = kp[1], kz = kp[2];
        float kn2 = fmaf(kz, kz, fmaf(ky, ky, kx*kx));
        f32x4 v = {kx, ky, kz, kn2};
        ((f32x4*)(ws + KX4_OFF))[idx] = v;
    }
}

// ---------------------------------------------------------------------------
// K2: Q[s][b][k][o] = b0_s[o] + W_s[o][0:3].kxyz + W_s[o][3:].feats
// ---------------------------------------------------------------------------
__global__ __launch_bounds__(256) void k_qproj(
    const float* __restrict__ kxyz, const float* __restrict__ feats,
    const float* __restrict__ w0, const float* __restrict__ b0,
    const float* __restrict__ w1, const float* __restrict__ b1,
    float* __restrict__ ws)
{
    __shared__ float wl[64*131];
    int bid  = blockIdx.x;
    int kgrp = bid & 511;
    int s    = (bid >> 9) & 1;
    int b    = bid >> 10;
    const float* W    = s ? w1 : w0;
    const float* bias = s ? b1 : b0;
    for (int i = threadIdx.x; i < 64*131; i += 256) wl[i] = W[i];
    __syncthreads();
    int k = kgrp*4 + (threadIdx.x >> 6);
    int o = threadIdx.x & 63;
    float acc = bias[o];
    const float* kp = kxyz + ((size_t)b*KPT + k)*3;
    acc = fmaf(wl[o*131+0], kp[0], acc);
    acc = fmaf(wl[o*131+1], kp[1], acc);
    acc = fmaf(wl[o*131+2], kp[2], acc);
    const float* f = feats + (size_t)b*CFEAT*KPT + k;
#pragma unroll 8
    for (int c = 0; c < CFEAT; ++c)
        acc = fmaf(wl[o*131+3+c], f[(size_t)c*KPT], acc);
    ws[Q0_OFF + (size_t)s*(2*KPT*64) + ((size_t)b*KPT + k)*64 + o] = acc;
}

// ---------------------------------------------------------------------------
// K3 main: one WAVE per point: dual-radius ball query + MFMA layer-2 + pool
// ---------------------------------------------------------------------------
template <int NST>
__device__ __forceinline__ void build_bfrag(
    const float* __restrict__ Qb, const int* __restrict__ idxl,
    const float* __restrict__ u_lds,
    bf16x8 (&Bhi)[NST][2], bf16x8 (&Blo)[NST][2], int lane)
{
    const int g = lane >> 4;
#pragma unroll
    for (int st = 0; st < NST; ++st) {
        int sp = idxl[st*16 + (lane & 15)];
        const float* qr = Qb + ((size_t)sp << 6) + g*8;
#pragma unroll
        for (int kc = 0; kc < 2; ++kc) {
            f32x4 q0 = *(const f32x4*)(qr + kc*32);
            f32x4 q1 = *(const f32x4*)(qr + kc*32 + 4);
            f32x4 u0 = *(const f32x4*)(u_lds + kc*32 + g*8);
            f32x4 u1 = *(const f32x4*)(u_lds + kc*32 + g*8 + 4);
            union { unsigned short u16[8]; bf16x8 v; } hh, hl;
#pragma unroll
            for (int j = 0; j < 4; ++j) {
                float x = fmaxf(q0[j] - u0[j], 0.f);
                unsigned short hi = bf_rne(x);
                hh.u16[j] = hi;
                hl.u16[j] = bf_rne(x - bf_f32(hi));
                float y = fmaxf(q1[j] - u1[j], 0.f);
                unsigned short hi2 = bf_rne(y);
                hh.u16[j+4] = hi2;
                hl.u16[j+4] = bf_rne(y - bf_f32(hi2));
            }
            Bhi[st][kc] = hh.v;
            Blo[st][kc] = hl.v;
        }
    }
}

template <int NST>
__device__ __forceinline__ void mfma_eval(
    const bf16x8* __restrict__ Ahi, const bf16x8* __restrict__ Alo,
    const float* __restrict__ bs,
    const bf16x8 (&Bhi)[NST][2], const bf16x8 (&Blo)[NST][2],
    float* __restrict__ stage, int sbase, int lane)
{
    const int g = lane >> 4;
#pragma unroll
    for (int ot = 0; ot < 4; ++ot) {
        int fi = (sbase + ot)*2;
        bf16x8 ah0 = Ahi[(fi+0)*64 + lane];
        bf16x8 ah1 = Ahi[(fi+1)*64 + lane];
        bf16x8 al0 = Alo[(fi+0)*64 + lane];
        bf16x8 al1 = Alo[(fi+1)*64 + lane];
        f32x4 bv = *(const f32x4*)(bs + ot*16 + g*4);
        f32x4 rmax = {0.f, 0.f, 0.f, 0.f};
#pragma unroll
        for (int st = 0; st < NST; ++st) {
            f32x4 acc = {0.f, 0.f, 0.f, 0.f};
            acc = __builtin_amdgcn_mfma_f32_16x16x32_bf16(al0, Bhi[st][0], acc, 0,0,0);
            acc = __builtin_amdgcn_mfma_f32_16x16x32_bf16(al1, Bhi[st][1], acc, 0,0,0);
            acc = __builtin_amdgcn_mfma_f32_16x16x32_bf16(ah0, Blo[st][0], acc, 0,0,0);
            acc = __builtin_amdgcn_mfma_f32_16x16x32_bf16(ah1, Blo[st][1], acc, 0,0,0);
            acc = __builtin_amdgcn_mfma_f32_16x16x32_bf16(ah0, Bhi[st][0], acc, 0,0,0);
            acc = __builtin_amdgcn_mfma_f32_16x16x32_bf16(ah1, Bhi[st][1], acc, 0,0,0);
#pragma unroll
            for (int r = 0; r < 4; ++r)
                rmax[r] = fmaxf(rmax[r], fmaxf(acc[r] + bv[r], 0.f));
        }
#pragma unroll
        for (int m = 1; m < 16; m <<= 1) {
#pragma unroll
            for (int r = 0; r < 4; ++r)
                rmax[r] = fmaxf(rmax[r], __shfl_xor(rmax[r], m));
        }
        if ((lane & 15) == 0)
            *(f32x4*)(stage + ot*16 + g*4) = rmax;
    }
}

__global__ __launch_bounds__(256) void k_main(
    const float* __restrict__ proposals, const float* __restrict__ grid_noise,
    const float* __restrict__ w00, const float* __restrict__ b01,
    const float* __restrict__ w10, const float* __restrict__ b11,
    float* __restrict__ ws)
{
    __shared__ int idx0s[4][NS0];
    __shared__ int idx1s[4][NS1];
    __shared__ __align__(16) float u0l[4][64], u1l[4][64];
    __shared__ __align__(16) float stage[4][64];
    const int wid  = threadIdx.x >> 6;
    const int lane = threadIdx.x & 63;

    const int p = blockIdx.x*4 + wid;            // < 20736
    int b   = p / NPT;
    int rem = p - b*NPT;
    int i   = rem / MGRID;
    int g   = rem - i*MGRID;

    float a0x = w00[lane*131+0], a0y = w00[lane*131+1], a0z = w00[lane*131+2];
    float a1x = w10[lane*131+0], a1y = w10[lane*131+1], a1z = w10[lane*131+2];

    const float* pr = proposals  + ((size_t)b*NPROP + i)*7;
    const float* gn = grid_noise + (((size_t)b*NPROP + i)*MGRID + g)*3;
    float gx = gn[0]*pr[3], gy = gn[1]*pr[4], gz = gn[2]*pr[5];
    float th = pr[6];
    float ss = sinf(th), cc = cosf(th);
    float nx = cc*gx - ss*gy + pr[0];
    float ny = ss*gx + cc*gy + pr[1];
    float nz = gz + pr[2];
    float pn2 = nx*nx + ny*ny + nz*nz;
    u0l[wid][lane] = a0x*nx + a0y*ny + a0z*nz;
    u1l[wid][lane] = a1x*nx + a1y*ny + a1z*nz;

    // ---- dual-radius ball query: one scan, 2-chunk unrolled ----
    int* idx0 = idx0s[wid];
    int* idx1 = idx1s[wid];
    int cnt0 = 0, cnt1 = 0;
    const f32x4* kx4 = (const f32x4*)(ws + KX4_OFF) + (size_t)b*KPT;
    ull ltm = (1ull << lane) - 1ull;

#define BQ_PROC(M, KK, CNT, IDX, NSV)                                         \
    if (M) {                                                                  \
        int pre = __popcll((M) & ltm);                                        \
        if ((((M) >> lane) & 1ull) && CNT + pre < NSV) IDX[CNT + pre] = (KK); \
        CNT += __popcll(M);                                                   \
    }

    for (int ck = 0; ck < KPT/64; ck += 2) {
        f32x4 ka = kx4[ck*64 + lane];
        f32x4 kc2 = kx4[ck*64 + 64 + lane];
        float dta = fmaf(nz, ka.z, fmaf(ny, ka.y, nx*ka.x));
        float d2a = fmaf(-2.f, dta, pn2 + ka.w);
        float dtb = fmaf(nz, kc2.z, fmaf(ny, kc2.y, nx*kc2.x));
        float d2b = fmaf(-2.f, dtb, pn2 + kc2.w);
        ull m0a = __ballot(d2a < R0SQ);
        ull m1a = __ballot(d2a < R1SQ);
        ull m0b = __ballot(d2b < R0SQ);
        ull m1b = __ballot(d2b < R1SQ);
        int kka = ck*64 + lane, kkb = kka + 64;
        BQ_PROC(m0a, kka, cnt0, idx0, NS0)
        BQ_PROC(m0b, kkb, cnt0, idx0, NS0)
        BQ_PROC(m1a, kka, cnt1, idx1, NS1)
        BQ_PROC(m1b, kkb, cnt1, idx1, NS1)
        if (cnt0 >= NS0 && cnt1 >= NS1) break;   // wave-uniform
    }
#undef BQ_PROC

    if (lane == 0) {
        if (cnt0 == 0) idx0[0] = 0;              // empty-ball fallback
        if (cnt1 == 0) idx1[0] = 0;
    }
    asm volatile("s_waitcnt lgkmcnt(0)" ::: "memory");
    __builtin_amdgcn_wave_barrier();
    int na0 = cnt0 ? min(cnt0, NS0) : 1;
    int na1 = cnt1 ? min(cnt1, NS1) : 1;
    int f0 = idx0[0], f1 = idx1[0];
    if (lane >= na0 && lane < NS0) idx0[lane] = f0;   // pad like reference
    if (lane >= na1 && lane < NS1) idx1[lane] = f1;
    asm volatile("s_waitcnt lgkmcnt(0)" ::: "memory");
    __builtin_amdgcn_wave_barrier();

    // ---- gather+convert B-fragments for BOTH scales, then MFMA ----
    const float*  Qb0 = ws + Q0_OFF + (size_t)b*(KPT*64);
    const float*  Qb1 = ws + Q0_OFF + (size_t)(2*KPT*64) + (size_t)b*(KPT*64);
    const bf16x8* Ahi = (const bf16x8*)(ws + AFRAG_OFF);
    const bf16x8* Alo = Ahi + 16*64;

    bf16x8 B0hi[1][2], B0lo[1][2], B1hi[2][2], B1lo[2][2];
    build_bfrag<1>(Qb0, idx0, u0l[wid], B0hi, B0lo, lane);
    build_bfrag<2>(Qb1, idx1, u1l[wid], B1hi, B1lo, lane);

    mfma_eval<1>(Ahi, Alo, b01, B0hi, B0lo, stage[wid], 0, lane);
    asm volatile("s_waitcnt lgkmcnt(0)" ::: "memory");
    __builtin_amdgcn_wave_barrier();
    float mx0 = stage[wid][lane];
    __builtin_amdgcn_wave_barrier();

    mfma_eval<2>(Ahi, Alo, b11, B1hi, B1lo, stage[wid], 4, lane);
    asm volatile("s_waitcnt lgkmcnt(0)" ::: "memory");
    __builtin_amdgcn_wave_barrier();
    float mx1 = stage[wid][lane];

    // coalesced pooled store: poolT[p][c]
    ws[POOL_OFF + (size_t)p*CFEAT + lane]      = mx0;
    ws[POOL_OFF + (size_t)p*CFEAT + 64 + lane] = mx1;
}

// ---------------------------------------------------------------------------
// K_ptr: pool2[r][c*216+g] = poolT[(r*216+g)][c]  (per-row transpose, 21 MB)
// ---------------------------------------------------------------------------
template <int W>
__device__ __forceinline__ void ptr_tile(const float* __restrict__ in,
                                         float* __restrict__ out,
                                         float* __restrict__ t, int g0)
{
    for (int idx = threadIdx.x; idx < 128*W; idx += 256) {
        int gg = idx >> 7, c = idx & 127;
        t[c*(W+1) + gg] = in[(size_t)(g0+gg)*128 + c];   // coalesced along c
    }
    __syncthreads();
    for (int idx = threadIdx.x; idx < 128*W; idx += 256) {
        int c = idx / W, gg = idx - c*W;
        out[c*216 + g0 + gg] = t[c*(W+1) + gg];          // coalesced along g
    }
}

__global__ __launch_bounds__(256) void k_ptr(float* __restrict__ ws)
{
    __shared__ float t[128*33];
    int bid = blockIdx.x;
    int row = bid / 7, tt = bid - row*7;
    const float* in = ws + POOL_OFF + (size_t)row*MGRID*CFEAT;
    float* out = ws + PT_OFF + (size_t)row*KRED;
    if (tt < 6) ptr_tile<32>(in, out, t, tt*32);
    else        ptr_tile<24>(in, out, t, 192);
}

// ---------------------------------------------------------------------------
// K4: part[ks][96][256] = A[96][ksK] * B[256][ksK]^T  (no atomics)
// grid = 108 ksplits x 2 o-tiles; K per split = 256 (4 chunks of 64)
// ---------------------------------------------------------------------------
__global__ __launch_bounds__(256) void k_red0(
    const float* __restrict__ A, const float* __restrict__ w0,
    float* __restrict__ part)
{
    __shared__ __align__(16) float Al[96*68];
    __shared__ __align__(16) float Bl[128*68];
    int bid = blockIdx.x;
    int ot  = bid & 1;
    int ks  = bid >> 1;                      // 0..107
    int tid = threadIdx.x;
    int tx  = tid & 15, ty = tid >> 4;
    float acc[6][8] = {};

    for (int chunk = 0; chunk < 4; ++chunk) {
        int kk0 = ks*256 + chunk*64;
#pragma unroll
        for (int j = 0; j < 6; ++j) {
            int f4i = tid + j*256;
            int rr = f4i >> 4, c4 = f4i & 15;
            float4 v = *(const float4*)(A + (size_t)rr*KRED + kk0 + c4*4);
            *(float4*)(Al + rr*68 + c4*4) = v;
        }
#pragma unroll
        for (int j = 0; j < 8; ++j) {
            int f4i = tid + j*256;
            int rr = f4i >> 4, c4 = f4i & 15;
            float4 v = *(const float4*)(w0 + (size_t)(ot*128+rr)*KRED + kk0 + c4*4);
            *(float4*)(Bl + rr*68 + c4*4) = v;
        }
        __syncthreads();
#pragma unroll
        for (int k4 = 0; k4 < 16; ++k4) {
            float4 av[6], bv[8];
#pragma unroll
            for (int q = 0; q < 6; ++q) av[q] = *(const float4*)(Al + (ty*6+q)*68 + k4*4);
#pragma unroll
            for (int u = 0; u < 8; ++u) bv[u] = *(const float4*)(Bl + (u*16+tx)*68 + k4*4);
#pragma unroll
            for (int q = 0; q < 6; ++q)
#pragma unroll
                for (int u = 0; u < 8; ++u) {
                    acc[q][u] = fmaf(av[q].x, bv[u].x, acc[q][u]);
                    acc[q][u] = fmaf(av[q].y, bv[u].y, acc[q][u]);
                    acc[q][u] = fmaf(av[q].z, bv[u].z, acc[q][u]);
                    acc[q][u] = fmaf(av[q].w, bv[u].w, acc[q][u]);
                }
        }
        __syncthreads();
    }
    float* pp = part + (size_t)ks*(96*256);
#pragma unroll
    for (int q = 0; q < 6; ++q)
#pragma unroll
        for (int u = 0; u < 8; ++u)
            pp[(size_t)(ty*6+q)*256 + ot*128 + u*16 + tx] = acc[q][u];
}

// ---------------------------------------------------------------------------
// K5: out = relu(relu(sum_ks part + b0) @ W1^T + b1)
// ---------------------------------------------------------------------------
__global__ __launch_bounds__(256) void k_fin(
    const float* __restrict__ part, const float* __restrict__ rb0,
    const float* __restrict__ w1, const float* __restrict__ rb1,
    float* __restrict__ out)
{
    __shared__ __align__(16) float hbuf[256];
    int r = blockIdx.x, o = threadIdx.x;
    const float* pp = part + (size_t)r*256 + o;
    float s0 = 0.f, s1 = 0.f, s2 = 0.f, s3 = 0.f;
#pragma unroll 4
    for (int ks = 0; ks < NKSPLIT; ks += 4) {
        s0 += pp[(size_t)(ks+0)*(96*256)];
        s1 += pp[(size_t)(ks+1)*(96*256)];
        s2 += pp[(size_t)(ks+2)*(96*256)];
        s3 += pp[(size_t)(ks+3)*(96*256)];
    }
    float h = fmaxf(((s0 + s1) + (s2 + s3)) + rb0[o], 0.f);
    hbuf[o] = h;
    __syncthreads();
    float a0 = rb1[o], a1 = 0.f, a2 = 0.f, a3 = 0.f;
    const float4* wrow = (const float4*)(w1 + (size_t)o*256);
    const float4* hv   = (const float4*)hbuf;
#pragma unroll 8
    for (int j = 0; j < 64; ++j) {
        float4 w = wrow[j], x = hv[j];
        a0 = fmaf(w.x, x.x, a0);
        a1 = fmaf(w.y, x.y, a1);
        a2 = fmaf(w.z, x.z, a2);
        a3 = fmaf(w.w, x.w, a3);
    }
    out[(size_t)r*256 + o] = fmaxf((a0 + a1) + (a2 + a3), 0.f);
}

// ---------------------------------------------------------------------------
extern "C" void kernel_launch(void* const* d_in, const int* in_sizes, int n_in,
                              void* d_out, int out_size, void* d_ws, size_t ws_size,
                              hipStream_t stream)
{
    (void)in_sizes; (void)n_in; (void)out_size; (void)ws_size;
    const float* proposals = (const float*)d_in[0];
    const float* kxyz      = (const float*)d_in[1];
    const float* feats     = (const float*)d_in[2];
    const float* gnoise    = (const float*)d_in[3];
    const float* w0_0 = (const float*)d_in[4];
    const float* b0_0 = (const float*)d_in[5];
    const float* w0_1 = (const float*)d_in[6];
    const float* b0_1 = (const float*)d_in[7];
    const float* w1_0 = (const float*)d_in[8];
    const float* b1_0 = (const float*)d_in[9];
    const float* w1_1 = (const float*)d_in[10];
    const float* b1_1 = (const float*)d_in[11];
    const float* rw0  = (const float*)d_in[12];
    const float* rb0  = (const float*)d_in[13];
    const float* rw1  = (const float*)d_in[14];
    const float* rb1  = (const float*)d_in[15];
    float* ws  = (float*)d_ws;
    float* out = (float*)d_out;

    k_pre  <<<  80,  64, 0, stream>>>(kxyz, w0_1, w1_1, ws);
    k_qproj<<<2048, 256, 0, stream>>>(kxyz, feats, w0_0, b0_0, w1_0, b1_0, ws);
    k_main <<<5184, 256, 0, stream>>>(proposals, gnoise,
                                      w0_0, b0_1, w1_0, b1_1, ws);
    k_ptr  <<< 672, 256, 0, stream>>>(ws);
    k_red0 <<< 216, 256, 0, stream>>>(ws + PT_OFF, rw0, ws + PART_OFF);
    k_fin  <<<  96, 256, 0, stream>>>(ws + PART_OFF, rb0, rw1, rb1, out);
}

// Round 7
// 247.619 us; speedup vs baseline: 1.9190x; 1.0459x over previous
//
#include <hip/hip_runtime.h>
#include <cstdint>

#define NPROP  48
#define MGRID  216
#define NPT    (NPROP*MGRID)      // 10368 points per batch
#define KPT    2048
#define CFEAT  128
#define R0SQ   0.64f              // 0.8^2
#define R1SQ   2.56f              // 1.6^2
#define NS0    16
#define NS1    32
#define KRED   (CFEAT*MGRID)      // 27648
#define NPOINTS (2*NPT)           // 20736
#define NKSPLIT 108               // K per split = 256

typedef float f32x4  __attribute__((ext_vector_type(4)));
typedef short bf16x8 __attribute__((ext_vector_type(8)));
typedef unsigned long long ull;

// workspace layout (floats) — total 8,511,488 fl = 34.0 MB (proven budget 41 MB)
#define AFRAG_OFF 0                           // A-frags hi+lo: 8192 floats (32 KB)
#define KX4_OFF   8192                        // kxyz4 [2][2048] f32x4 = 16384
#define Q0_OFF    24576                       // Q [2 s][2 b][2048 k][64 o] = 524288
#define POOL_OFF  548864                      // poolT [20736 p][128 c] = 2654208
#define PT_OFF    3203072                     // pool2 [96 r][27648 (c*216+g)] = 2654208
#define PART_OFF  5857280                     // part [108 ks][96 r][256 o] = 2654208

__device__ __forceinline__ unsigned short bf_rne(float x) {
    unsigned u = __float_as_uint(x);
    return (unsigned short)((u + 0x7fffu + ((u >> 16) & 1u)) >> 16);
}
__device__ __forceinline__ float bf_f32(unsigned short h) {
    return __uint_as_float(((unsigned)h) << 16);
}

// ---------------------------------------------------------------------------
// K0: blocks 0-15: layer-2 weight A-fragments (hi/lo bf16 split).
//     blocks 16-79: pack kxyz4 = (x,y,z,kn2) for the ball query.
// ---------------------------------------------------------------------------
__global__ __launch_bounds__(64) void k_pre(
    const float* __restrict__ kxyz,
    const float* __restrict__ w01, const float* __restrict__ w11,
    float* __restrict__ ws)
{
    int bid = blockIdx.x;
    if (bid < 16) {
        int kc = bid & 1, ot = (bid >> 1) & 3, s = bid >> 3;
        const float* W = s ? w11 : w01;
        int l   = threadIdx.x;
        int row = ot*16 + (l & 15);
        int k0  = kc*32 + (l >> 4)*8;
        union { unsigned short u16[8]; bf16x8 v; } hh, hl;
#pragma unroll
        for (int j = 0; j < 8; ++j) {
            float x  = W[row*64 + k0 + j];
            unsigned short hi = bf_rne(x);
            hh.u16[j] = hi;
            hl.u16[j] = bf_rne(x - bf_f32(hi));
        }
        bf16x8* Ahi = (bf16x8*)(ws + AFRAG_OFF);
        bf16x8* Alo = Ahi + 16*64;
        int fi = (s*4 + ot)*2 + kc;
        Ahi[fi*64 + l] = hh.v;
        Alo[fi*64 + l] = hl.v;
    } else {
        int idx = (bid - 16)*64 + threadIdx.x;      // = b*KPT + k, < 4096
        const float* kp = kxyz + (size_t)idx*3;
        float kx = kp[0], ky = kp[1], kz = kp[2];
        float kn2 = fmaf(kz, kz, fmaf(ky, ky, kx*kx));
        f32x4 v = {kx, ky, kz, kn2};
        ((f32x4*)(ws + KX4_OFF))[idx] = v;
    }
}

// ---------------------------------------------------------------------------
// K2: Q[s][b][k][o] = b0_s[o] + W_s[o][0:3].kxyz + W_s[o][3:].feats
// ---------------------------------------------------------------------------
__global__ __launch_bounds__(256) void k_qproj(
    const float* __restrict__ kxyz, const float* __restrict__ feats,
    const float* __restrict__ w0, const float* __restrict__ b0,
    const float* __restrict__ w1, const float* __restrict__ b1,
    float* __restrict__ ws)
{
    __shared__ float wl[64*131];
    int bid  = blockIdx.x;
    int kgrp = bid & 511;
    int s    = (bid >> 9) & 1;
    int b    = bid >> 10;
    const float* W    = s ? w1 : w0;
    const float* bias = s ? b1 : b0;
    for (int i = threadIdx.x; i < 64*131; i += 256) wl[i] = W[i];
    __syncthreads();
    int k = kgrp*4 + (threadIdx.x >> 6);
    int o = threadIdx.x & 63;
    float acc = bias[o];
    const float* kp = kxyz + ((size_t)b*KPT + k)*3;
    acc = fmaf(wl[o*131+0], kp[0], acc);
    acc = fmaf(wl[o*131+1], kp[1], acc);
    acc = fmaf(wl[o*131+2], kp[2], acc);
    const float* f = feats + (size_t)b*CFEAT*KPT + k;
#pragma unroll 8
    for (int c = 0; c < CFEAT; ++c)
        acc = fmaf(wl[o*131+3+c], f[(size_t)c*KPT], acc);
    ws[Q0_OFF + (size_t)s*(2*KPT*64) + ((size_t)b*KPT + k)*64 + o] = acc;
}

// ---------------------------------------------------------------------------
// K3 main: one WAVE per point: dual-radius ball query + MFMA layer-2 + pool
// A-fragments staged in LDS (block-cooperative) to kill per-wave L2 gathers.
// ---------------------------------------------------------------------------
template <int NST>
__device__ __forceinline__ void build_bfrag(
    const float* __restrict__ Qb, const int* __restrict__ idxl,
    const float* __restrict__ u_lds,
    bf16x8 (&Bhi)[NST][2], bf16x8 (&Blo)[NST][2], int lane)
{
    const int g = lane >> 4;
#pragma unroll
    for (int st = 0; st < NST; ++st) {
        int sp = idxl[st*16 + (lane & 15)];
        const float* qr = Qb + ((size_t)sp << 6) + g*8;
#pragma unroll
        for (int kc = 0; kc < 2; ++kc) {
            f32x4 q0 = *(const f32x4*)(qr + kc*32);
            f32x4 q1 = *(const f32x4*)(qr + kc*32 + 4);
            f32x4 u0 = *(const f32x4*)(u_lds + kc*32 + g*8);
            f32x4 u1 = *(const f32x4*)(u_lds + kc*32 + g*8 + 4);
            union { unsigned short u16[8]; bf16x8 v; } hh, hl;
#pragma unroll
            for (int j = 0; j < 4; ++j) {
                float x = fmaxf(q0[j] - u0[j], 0.f);
                unsigned short hi = bf_rne(x);
                hh.u16[j] = hi;
                hl.u16[j] = bf_rne(x - bf_f32(hi));
                float y = fmaxf(q1[j] - u1[j], 0.f);
                unsigned short hi2 = bf_rne(y);
                hh.u16[j+4] = hi2;
                hl.u16[j+4] = bf_rne(y - bf_f32(hi2));
            }
            Bhi[st][kc] = hh.v;
            Blo[st][kc] = hl.v;
        }
    }
}

template <int NST>
__device__ __forceinline__ void mfma_eval(
    const bf16x8* Ahi, const bf16x8* Alo,   // LDS pointers
    const float* __restrict__ bs,
    const bf16x8 (&Bhi)[NST][2], const bf16x8 (&Blo)[NST][2],
    float* stage, int sbase, int lane)
{
    const int g = lane >> 4;
#pragma unroll
    for (int ot = 0; ot < 4; ++ot) {
        int fi = (sbase + ot)*2;
        bf16x8 ah0 = Ahi[(fi+0)*64 + lane];
        bf16x8 ah1 = Ahi[(fi+1)*64 + lane];
        bf16x8 al0 = Alo[(fi+0)*64 + lane];
        bf16x8 al1 = Alo[(fi+1)*64 + lane];
        f32x4 bv = *(const f32x4*)(bs + ot*16 + g*4);
        f32x4 rmax = {0.f, 0.f, 0.f, 0.f};
#pragma unroll
        for (int st = 0; st < NST; ++st) {
            f32x4 acc = {0.f, 0.f, 0.f, 0.f};
            acc = __builtin_amdgcn_mfma_f32_16x16x32_bf16(al0, Bhi[st][0], acc, 0,0,0);
            acc = __builtin_amdgcn_mfma_f32_16x16x32_bf16(al1, Bhi[st][1], acc, 0,0,0);
            acc = __builtin_amdgcn_mfma_f32_16x16x32_bf16(ah0, Blo[st][0], acc, 0,0,0);
            acc = __builtin_amdgcn_mfma_f32_16x16x32_bf16(ah1, Blo[st][1], acc, 0,0,0);
            acc = __builtin_amdgcn_mfma_f32_16x16x32_bf16(ah0, Bhi[st][0], acc, 0,0,0);
            acc = __builtin_amdgcn_mfma_f32_16x16x32_bf16(ah1, Bhi[st][1], acc, 0,0,0);
#pragma unroll
            for (int r = 0; r < 4; ++r)
                rmax[r] = fmaxf(rmax[r], fmaxf(acc[r] + bv[r], 0.f));
        }
#pragma unroll
        for (int m = 1; m < 16; m <<= 1) {
#pragma unroll
            for (int r = 0; r < 4; ++r)
                rmax[r] = fmaxf(rmax[r], __shfl_xor(rmax[r], m));
        }
        if ((lane & 15) == 0)
            *(f32x4*)(stage + ot*16 + g*4) = rmax;
    }
}

__global__ __launch_bounds__(256) void k_main(
    const float* __restrict__ proposals, const float* __restrict__ grid_noise,
    const float* __restrict__ w00, const float* __restrict__ b01,
    const float* __restrict__ w10, const float* __restrict__ b11,
    float* __restrict__ ws)
{
    __shared__ __align__(16) float afrag[8192];      // 32 KB: Ahi[16][64] | Alo[16][64]
    __shared__ int idx0s[4][NS0];
    __shared__ int idx1s[4][NS1];
    __shared__ __align__(16) float u0l[4][64], u1l[4][64];
    __shared__ __align__(16) float stage[4][64];
    const int wid  = threadIdx.x >> 6;
    const int lane = threadIdx.x & 63;

    // ---- cooperative stage of all A-fragments into LDS (once per block)
    {
        const f32x4* src = (const f32x4*)(ws + AFRAG_OFF);
        f32x4* dst = (f32x4*)afrag;
        for (int t = threadIdx.x; t < 2048; t += 256) dst[t] = src[t];
    }
    __syncthreads();

    const int p = blockIdx.x*4 + wid;            // < 20736
    int b   = p / NPT;
    int rem = p - b*NPT;
    int i   = rem / MGRID;
    int g   = rem - i*MGRID;

    float a0x = w00[lane*131+0], a0y = w00[lane*131+1], a0z = w00[lane*131+2];
    float a1x = w10[lane*131+0], a1y = w10[lane*131+1], a1z = w10[lane*131+2];

    const float* pr = proposals  + ((size_t)b*NPROP + i)*7;
    const float* gn = grid_noise + (((size_t)b*NPROP + i)*MGRID + g)*3;
    float gx = gn[0]*pr[3], gy = gn[1]*pr[4], gz = gn[2]*pr[5];
    float th = pr[6];
    float ss = sinf(th), cc = cosf(th);
    float nx = cc*gx - ss*gy + pr[0];
    float ny = ss*gx + cc*gy + pr[1];
    float nz = gz + pr[2];
    float pn2 = nx*nx + ny*ny + nz*nz;
    u0l[wid][lane] = a0x*nx + a0y*ny + a0z*nz;
    u1l[wid][lane] = a1x*nx + a1y*ny + a1z*nz;

    // ---- dual-radius ball query: one scan, per-radius guarded processing
    int* idx0 = idx0s[wid];
    int* idx1 = idx1s[wid];
    int cnt0 = 0, cnt1 = 0;
    const f32x4* kx4 = (const f32x4*)(ws + KX4_OFF) + (size_t)b*KPT;
    ull ltm = (1ull << lane) - 1ull;

#define BQ_PROC(D2, RSQ, KK, CNT, IDX, NSV)                                   \
    {                                                                         \
        ull m = __ballot((D2) < RSQ);                                         \
        if (m) {                                                              \
            int pre = __popcll(m & ltm);                                      \
            if (((m >> lane) & 1ull) && CNT + pre < NSV) IDX[CNT + pre] = (KK);\
            CNT += __popcll(m);                                               \
        }                                                                     \
    }

    for (int ck = 0; ck < KPT/64; ck += 2) {
        f32x4 ka  = kx4[ck*64 + lane];
        f32x4 kc2 = kx4[ck*64 + 64 + lane];
        float dta = fmaf(nz, ka.z, fmaf(ny, ka.y, nx*ka.x));
        float d2a = fmaf(-2.f, dta, pn2 + ka.w);
        float dtb = fmaf(nz, kc2.z, fmaf(ny, kc2.y, nx*kc2.x));
        float d2b = fmaf(-2.f, dtb, pn2 + kc2.w);
        int kka = ck*64 + lane, kkb = kka + 64;
        if (cnt0 < NS0) {                        // wave-uniform guard
            BQ_PROC(d2a, R0SQ, kka, cnt0, idx0, NS0)
            BQ_PROC(d2b, R0SQ, kkb, cnt0, idx0, NS0)
        }
        if (cnt1 < NS1) {                        // wave-uniform guard
            BQ_PROC(d2a, R1SQ, kka, cnt1, idx1, NS1)
            BQ_PROC(d2b, R1SQ, kkb, cnt1, idx1, NS1)
        }
        if (cnt0 >= NS0 && cnt1 >= NS1) break;   // wave-uniform
    }
#undef BQ_PROC

    if (lane == 0) {
        if (cnt0 == 0) idx0[0] = 0;              // empty-ball fallback
        if (cnt1 == 0) idx1[0] = 0;
    }
    asm volatile("s_waitcnt lgkmcnt(0)" ::: "memory");
    __builtin_amdgcn_wave_barrier();
    int na0 = cnt0 ? min(cnt0, NS0) : 1;
    int na1 = cnt1 ? min(cnt1, NS1) : 1;
    int f0 = idx0[0], f1 = idx1[0];
    if (lane >= na0 && lane < NS0) idx0[lane] = f0;   // pad like reference
    if (lane >= na1 && lane < NS1) idx1[lane] = f1;
    asm volatile("s_waitcnt lgkmcnt(0)" ::: "memory");
    __builtin_amdgcn_wave_barrier();

    // ---- gather+convert B-fragments for BOTH scales, then MFMA ----
    const float*  Qb0 = ws + Q0_OFF + (size_t)b*(KPT*64);
    const float*  Qb1 = ws + Q0_OFF + (size_t)(2*KPT*64) + (size_t)b*(KPT*64);
    const bf16x8* Ahi = (const bf16x8*)afrag;         // LDS
    const bf16x8* Alo = Ahi + 16*64;

    bf16x8 B0hi[1][2], B0lo[1][2], B1hi[2][2], B1lo[2][2];
    build_bfrag<1>(Qb0, idx0, u0l[wid], B0hi, B0lo, lane);
    build_bfrag<2>(Qb1, idx1, u1l[wid], B1hi, B1lo, lane);

    mfma_eval<1>(Ahi, Alo, b01, B0hi, B0lo, stage[wid], 0, lane);
    asm volatile("s_waitcnt lgkmcnt(0)" ::: "memory");
    __builtin_amdgcn_wave_barrier();
    float mx0 = stage[wid][lane];
    __builtin_amdgcn_wave_barrier();

    mfma_eval<2>(Ahi, Alo, b11, B1hi, B1lo, stage[wid], 4, lane);
    asm volatile("s_waitcnt lgkmcnt(0)" ::: "memory");
    __builtin_amdgcn_wave_barrier();
    float mx1 = stage[wid][lane];

    // coalesced pooled store: poolT[p][c]
    ws[POOL_OFF + (size_t)p*CFEAT + lane]      = mx0;
    ws[POOL_OFF + (size_t)p*CFEAT + 64 + lane] = mx1;
}

// ---------------------------------------------------------------------------
// K_ptr: pool2[r][c*216+g] = poolT[(r*216+g)][c]  (per-row transpose, 21 MB)
// ---------------------------------------------------------------------------
template <int W>
__device__ __forceinline__ void ptr_tile(const float* __restrict__ in,
                                         float* __restrict__ out,
                                         float* __restrict__ t, int g0)
{
    for (int idx = threadIdx.x; idx < 128*W; idx += 256) {
        int gg = idx >> 7, c = idx & 127;
        t[c*(W+1) + gg] = in[(size_t)(g0+gg)*128 + c];   // coalesced along c
    }
    __syncthreads();
    for (int idx = threadIdx.x; idx < 128*W; idx += 256) {
        int c = idx / W, gg = idx - c*W;
        out[c*216 + g0 + gg] = t[c*(W+1) + gg];          // coalesced along g
    }
}

__global__ __launch_bounds__(256) void k_ptr(float* __restrict__ ws)
{
    __shared__ float t[128*33];
    int bid = blockIdx.x;
    int row = bid / 7, tt = bid - row*7;
    const float* in = ws + POOL_OFF + (size_t)row*MGRID*CFEAT;
    float* out = ws + PT_OFF + (size_t)row*KRED;
    if (tt < 6) ptr_tile<32>(in, out, t, tt*32);
    else        ptr_tile<24>(in, out, t, 192);
}

// ---------------------------------------------------------------------------
// K4: part[ks][96][256] = A[96][ksK] * B[256][ksK]^T  (no atomics)
// grid = 108 ksplits x 4 o-tiles of 64; K per split = 256 (4 chunks of 64)
// ---------------------------------------------------------------------------
__global__ __launch_bounds__(256) void k_red0(
    const float* __restrict__ A, const float* __restrict__ w0,
    float* __restrict__ part)
{
    __shared__ __align__(16) float Al[96*68];
    __shared__ __align__(16) float Bl[64*68];
    int bid = blockIdx.x;
    int ot  = bid & 3;
    int ks  = bid >> 2;                      // 0..107
    int tid = threadIdx.x;
    int tx  = tid & 15, ty = tid >> 4;
    float acc[6][4] = {};

    for (int chunk = 0; chunk < 4; ++chunk) {
        int kk0 = ks*256 + chunk*64;
#pragma unroll
        for (int j = 0; j < 6; ++j) {        // stage A 96x64
            int f4i = tid + j*256;
            int rr = f4i >> 4, c4 = f4i & 15;
            float4 v = *(const float4*)(A + (size_t)rr*KRED + kk0 + c4*4);
            *(float4*)(Al + rr*68 + c4*4) = v;
        }
#pragma unroll
        for (int j = 0; j < 4; ++j) {        // stage B 64x64
            int f4i = tid + j*256;
            int rr = f4i >> 4, c4 = f4i & 15;
            float4 v = *(const float4*)(w0 + (size_t)(ot*64+rr)*KRED + kk0 + c4*4);
            *(float4*)(Bl + rr*68 + c4*4) = v;
        }
        __syncthreads();
#pragma unroll
        for (int k4 = 0; k4 < 16; ++k4) {
            float4 av[6], bv[4];
#pragma unroll
            for (int q = 0; q < 6; ++q) av[q] = *(const float4*)(Al + (ty*6+q)*68 + k4*4);
#pragma unroll
            for (int u = 0; u < 4; ++u) bv[u] = *(const float4*)(Bl + (u*16+tx)*68 + k4*4);
#pragma unroll
            for (int q = 0; q < 6; ++q)
#pragma unroll
                for (int u = 0; u < 4; ++u) {
                    acc[q][u] = fmaf(av[q].x, bv[u].x, acc[q][u]);
                    acc[q][u] = fmaf(av[q].y, bv[u].y, acc[q][u]);
                    acc[q][u] = fmaf(av[q].z, bv[u].z, acc[q][u]);
                    acc[q][u] = fmaf(av[q].w, bv[u].w, acc[q][u]);
                }
        }
        __syncthreads();
    }
    float* pp = part + (size_t)ks*(96*256);
#pragma unroll
    for (int q = 0; q < 6; ++q)
#pragma unroll
        for (int u = 0; u < 4; ++u)
            pp[(size_t)(ty*6+q)*256 + ot*64 + u*16 + tx] = acc[q][u];
}

// ---------------------------------------------------------------------------
// K5: out = relu(relu(sum_ks part + b0) @ W1^T + b1)
// ---------------------------------------------------------------------------
__global__ __launch_bounds__(256) void k_fin(
    const float* __restrict__ part, const float* __restrict__ rb0,
    const float* __restrict__ w1, const float* __restrict__ rb1,
    float* __restrict__ out)
{
    __shared__ __align__(16) float hbuf[256];
    int r = blockIdx.x, o = threadIdx.x;
    const float* pp = part + (size_t)r*256 + o;
    float s0 = 0.f, s1 = 0.f, s2 = 0.f, s3 = 0.f;
#pragma unroll 4
    for (int ks = 0; ks < NKSPLIT; ks += 4) {
        s0 += pp[(size_t)(ks+0)*(96*256)];
        s1 += pp[(size_t)(ks+1)*(96*256)];
        s2 += pp[(size_t)(ks+2)*(96*256)];
        s3 += pp[(size_t)(ks+3)*(96*256)];
    }
    float h = fmaxf(((s0 + s1) + (s2 + s3)) + rb0[o], 0.f);
    hbuf[o] = h;
    __syncthreads();
    float a0 = rb1[o], a1 = 0.f, a2 = 0.f, a3 = 0.f;
    const float4* wrow = (const float4*)(w1 + (size_t)o*256);
    const float4* hv   = (const float4*)hbuf;
#pragma unroll 8
    for (int j = 0; j < 64; ++j) {
        float4 w = wrow[j], x = hv[j];
        a0 = fmaf(w.x, x.x, a0);
        a1 = fmaf(w.y, x.y, a1);
        a2 = fmaf(w.z, x.z, a2);
        a3 = fmaf(w.w, x.w, a3);
    }
    out[(size_t)r*256 + o] = fmaxf((a0 + a1) + (a2 + a3), 0.f);
}

// ---------------------------------------------------------------------------
extern "C" void kernel_launch(void* const* d_in, const int* in_sizes, int n_in,
                              void* d_out, int out_size, void* d_ws, size_t ws_size,
                              hipStream_t stream)
{
    (void)in_sizes; (void)n_in; (void)out_size; (void)ws_size;
    const float* proposals = (const float*)d_in[0];
    const float* kxyz      = (const float*)d_in[1];
    const float* feats     = (const float*)d_in[2];
    const float* gnoise    = (const float*)d_in[3];
    const float* w0_0 = (const float*)d_in[4];
    const float* b0_0 = (const float*)d_in[5];
    const float* w0_1 = (const float*)d_in[6];
    const float* b0_1 = (const float*)d_in[7];
    const float* w1_0 = (const float*)d_in[8];
    const float* b1_0 = (const float*)d_in[9];
    const float* w1_1 = (const float*)d_in[10];
    const float* b1_1 = (const float*)d_in[11];
    const float* rw0  = (const float*)d_in[12];
    const float* rb0  = (const float*)d_in[13];
    const float* rw1  = (const float*)d_in[14];
    const float* rb1  = (const float*)d_in[15];
    float* ws  = (float*)d_ws;
    float* out = (float*)d_out;

    k_pre  <<<  80,  64, 0, stream>>>(kxyz, w0_1, w1_1, ws);
    k_qproj<<<2048, 256, 0, stream>>>(kxyz, feats, w0_0, b0_0, w1_0, b1_0, ws);
    k_main <<<5184, 256, 0, stream>>>(proposals, gnoise,
                                      w0_0, b0_1, w1_0, b1_1, ws);
    k_ptr  <<< 672, 256, 0, stream>>>(ws);
    k_red0 <<< 432, 256, 0, stream>>>(ws + PT_OFF, rw0, ws + PART_OFF);
    k_fin  <<<  96, 256, 0, stream>>>(ws + PART_OFF, rb0, rw1, rb1, out);
}